// Round 11
// baseline (64.742 us; speedup 1.0000x reference)
//
#include <hip/hip_runtime.h>

#define H_ 128
#define W_ 128
#define HW 16384
#define C_ 64
#define O_ 64
#define N_ 8

typedef __attribute__((ext_vector_type(4))) float f32x4;
typedef __attribute__((ext_vector_type(2))) _Float16 f16x2;
typedef __attribute__((ext_vector_type(8))) _Float16 f16x8;

__device__ __forceinline__ unsigned short f2h(float f) {
    union { _Float16 h; unsigned short u; } c;
    c.h = (_Float16)f;
    return c.u;
}

// ---- prep 1: x NCHW fp32 -> xt NHWC f16, XCD-aligned (n = bid&7) ----
__global__ __launch_bounds__(256) void nchw2nhwc(const float* __restrict__ x,
                                                 unsigned short* __restrict__ xt) {
    const int bid = blockIdx.x;
    const int n = bid & 7;
    const int rest = bid >> 3;
    const int wt = rest & 3, h = rest >> 2;
    const int w0 = wt * 32;
    __shared__ unsigned short tile[32][65];
    const int tid = threadIdx.x;
    const int wl = tid & 31, cg = tid >> 5;
#pragma unroll
    for (int r = 0; r < 8; ++r) {
        const int c = cg * 8 + r;
        const float v = x[(((size_t)(n * 64 + c) * 128 + h) * 128) + w0 + wl];
        tile[wl][c] = f2h(v);
    }
    __syncthreads();
    const int c2 = tid & 63, wg = tid >> 6;
#pragma unroll
    for (int r = 0; r < 8; ++r) {
        const int w = wg * 8 + r;
        xt[(((size_t)(n * 128 + h) * 128 + w0 + w) << 6) + c2] = tile[w][c2];
    }
}

// ---- prep 2: weight [O][C][3][3] fp32 -> B-fragment-packed f16 ----
__global__ void bpack_kernel(const float* __restrict__ w, unsigned short* __restrict__ bp) {
    const int idx = blockIdx.x * 256 + threadIdx.x;
    if (idx >= 36864) return;
    const int i = idx & 7;
    const int lane = (idx >> 3) & 63;
    const int ot = (idx >> 9) & 3;
    const int h = (idx >> 11) & 1;
    const int j = idx >> 12;
    const int o = ot * 16 + (lane & 15);
    const int c = h * 32 + (lane >> 4) * 8 + i;
    bp[idx] = f2h(w[(o * 64 + c) * 9 + j]);
}

// ---- prep 3: tap plan. Per (n, j, pix): meta u32 + packed f16 weights x2 ----
// ok (bit31=1): meta = 0x80000000 | k00(bits0-11) | dx<<12 | dy<<13
//   k00 = ((sy0*28+sx0)<<2) | (sx0&3)  -> consumer index = k00 ^ lgrp (+112*dy etc.)
// !ok (bit31=0): meta = gpos<<16 | dx<<1 | dy   (gpos = y0c*128+x0c)
//   low 12 bits are 0 -> speculative LDS reads stay in-bounds.
// Tile geometry MUST match main: t = ho&~7, tx0 = wo&~15, margins 6 (halo 20x28).
__global__ __launch_bounds__(256) void plan_kernel(const float* __restrict__ off,
                                                   unsigned* __restrict__ metap,
                                                   unsigned* __restrict__ w01p,
                                                   unsigned* __restrict__ w23p) {
    const int bid = blockIdx.x;        // 4608 = 8n * 9j * 64 pixblocks
    const int n = bid & 7;
    const int rem = bid >> 3;          // 0..575
    const int j = rem >> 6;            // 0..8
    const int pix = ((rem & 63) << 8) + threadIdx.x;
    const int kh = j / 3, kw = j - kh * 3;
    const int ho = pix >> 7, wo = pix & 127;

    const float* ob = off + (size_t)(n * 18 + 2 * j) * HW + pix;
    const float oy = ob[0];
    const float ox = ob[HW];
    const float py = (float)(ho - 1 + kh) + oy;
    const float px = (float)(wo - 1 + kw) + ox;
    const float y0f = floorf(py), x0f = floorf(px);
    const float wy = py - y0f, wx = px - x0f;
    const int y0 = (int)y0f, x0 = (int)x0f;
    const bool vy0 = (unsigned)y0 < 128u;
    const bool vy1 = (unsigned)(y0 + 1) < 128u;
    const bool vx0 = (unsigned)x0 < 128u;
    const bool vx1 = (unsigned)(x0 + 1) < 128u;
    const int y0c = min(max(y0, 0), 127), y1c = min(max(y0 + 1, 0), 127);
    const int x0c = min(max(x0, 0), 127), x1c = min(max(x0 + 1, 0), 127);
    const float s00 = (1.f - wy) * (1.f - wx) * ((vy0 & vx0) ? 1.f : 0.f);
    const float s01 = (1.f - wy) * wx * ((vy0 & vx1) ? 1.f : 0.f);
    const float s10 = wy * (1.f - wx) * ((vy1 & vx0) ? 1.f : 0.f);
    const float s11 = wy * wx * ((vy1 & vx1) ? 1.f : 0.f);

    const int t = ho & ~7, tx0 = wo & ~15;
    const int sy0 = y0c - t + 6, sy1 = y1c - t + 6;
    const int sx0 = x0c - tx0 + 6, sx1 = x1c - tx0 + 6;
    const bool ok = ((unsigned)sy0 <= 19u) & ((unsigned)sy1 <= 19u) &
                    ((unsigned)sx0 <= 27u) & ((unsigned)sx1 <= 27u);
    unsigned meta;
    if (ok) {
        const unsigned k00 = ((unsigned)(sy0 * 28 + sx0) << 2) | (unsigned)(sx0 & 3);
        meta = 0x80000000u | k00 | ((unsigned)(x1c - x0c) << 12) | ((unsigned)(y1c - y0c) << 13);
    } else {
        meta = ((unsigned)(y0c * 128 + x0c) << 16) | ((unsigned)(x1c - x0c) << 1) | (unsigned)(y1c - y0c);
    }
    const size_t e = (size_t)(n * 9 + j) * HW + pix;
    metap[e] = meta;
    w01p[e] = (unsigned)f2h(s00) | ((unsigned)f2h(s01) << 16);
    w23p[e] = (unsigned)f2h(s10) | ((unsigned)f2h(s11) << 16);
}

// ---- main: 16(w)x8(h) tile, 1024 blocks = 4/CU; coords from precomputed plan ----
__global__ __launch_bounds__(256, 4) void dcn_mfma(const unsigned short* __restrict__ xt,
                                                   const unsigned* __restrict__ metap,
                                                   const unsigned* __restrict__ w01p,
                                                   const unsigned* __restrict__ w23p,
                                                   const unsigned short* __restrict__ bp,
                                                   float* __restrict__ out) {
    __shared__ uint4 lds4[2240];   // 20*28 positions * 4 chunks (one 32-ch half)

    const int tid = threadIdx.x;
    const int lane = tid & 63;
    const int wid = tid >> 6;
    const int lrow = lane & 15;
    const int lgrp = lane >> 4;

    const int bid = blockIdx.x;
    const int n = bid & 7;
    const int tile = bid >> 3;
    const int t   = (tile >> 3) << 3;
    const int tx0 = (tile & 7) << 4;

    const unsigned short* xn = xt + (size_t)n * (HW * 64);
    const unsigned char* xb = (const unsigned char*)xn;
    const f16x8* bg = (const f16x8*)bp;
    const size_t nplane = (size_t)n * 9 * HW;
    const unsigned* mp  = metap + nplane;
    const unsigned* wpa = w01p + nplane;
    const unsigned* wpb = w23p + nplane;

    f32x4 acc[2][4];
#pragma unroll
    for (int q = 0; q < 2; ++q)
#pragma unroll
        for (int r = 0; r < 4; ++r) acc[q][r] = (f32x4){0.f, 0.f, 0.f, 0.f};

#pragma unroll 1
    for (int h = 0; h < 2; ++h) {
        if (h) __syncthreads();
        for (int c = tid; c < 560; c += 256) {
            const int ry = c / 28, rx = c - ry * 28;
            const int gy = min(max(t - 6 + ry, 0), 127);
            const int gx = min(max(tx0 - 6 + rx, 0), 127);
            const uint4* src = (const uint4*)(xn + ((((gy << 7) + gx) << 6) | (h << 5)));
            const int d = c << 2, sw = rx & 3;
#pragma unroll
            for (int sub = 0; sub < 4; ++sub) lds4[d + (sub ^ sw)] = src[sub];
        }
        __syncthreads();

#pragma unroll
        for (int q = 0; q < 2; ++q) {
            const int ho = t + (wid << 1) + q;
            const int pixb = (ho << 7) + tx0 + lrow;

#pragma unroll 3
            for (int j = 0; j < 9; ++j) {
                const int e = j * HW + pixb;
                const unsigned meta = mp[e];
                const unsigned wab = wpa[e];
                const unsigned wcd = wpb[e];
                union { unsigned u; f16x2 h2; } W00, W01, W10, W11;
                W00.u = __builtin_amdgcn_perm(wab, wab, 0x01000100u);
                W01.u = __builtin_amdgcn_perm(wab, wab, 0x03020302u);
                W10.u = __builtin_amdgcn_perm(wcd, wcd, 0x01000100u);
                W11.u = __builtin_amdgcn_perm(wcd, wcd, 0x03020302u);

                const bool ok = (int)meta < 0;
                const unsigned k00 = meta & 0xfffu;
                const unsigned dx = (meta >> 12) & 1u;
                const unsigned k01 = ((k00 & ~3u) + (dx << 2)) | (((k00 & 3u) + dx) & 3u);
                const unsigned dyi = (meta & 0x2000u) ? 112u : 0u;
                const unsigned k10 = k00 + dyi, k11 = k01 + dyi;

                uint4 T00 = lds4[k00 ^ (unsigned)lgrp];
                uint4 T01 = lds4[k01 ^ (unsigned)lgrp];
                uint4 T10 = lds4[k10 ^ (unsigned)lgrp];
                uint4 T11 = lds4[k11 ^ (unsigned)lgrp];
                if (!__all(ok)) {   // rare: tap beyond halo -> exact global path
                    if (!ok) {
                        const unsigned gpos = (meta >> 16) & 0x3fffu;
                        const int dxo = (int)((meta >> 1) & 1u) << 7;
                        const int dyo = (int)(meta & 1u) << 14;
                        const unsigned char* p = xb + ((gpos << 7) | (h << 6)) + (lgrp << 4);
                        T00 = *(const uint4*)p;
                        T01 = *(const uint4*)(p + dxo);
                        T10 = *(const uint4*)(p + dyo);
                        T11 = *(const uint4*)(p + dyo + dxo);
                    }
                }
                union { uint4 u; f16x2 h2[4]; f16x8 v; } A, U00, U01, U10, U11;
                U00.u = T00; U01.u = T01; U10.u = T10; U11.u = T11;
#pragma unroll
                for (int k = 0; k < 4; ++k)
                    A.h2[k] = U00.h2[k] * W00.h2 + U01.h2[k] * W01.h2
                            + U10.h2[k] * W10.h2 + U11.h2[k] * W11.h2;
                const int fb = ((j * 2 + h) << 8) + lane;
                acc[q][0] = __builtin_amdgcn_mfma_f32_16x16x32_f16(A.v, bg[fb],       acc[q][0], 0, 0, 0);
                acc[q][1] = __builtin_amdgcn_mfma_f32_16x16x32_f16(A.v, bg[fb + 64],  acc[q][1], 0, 0, 0);
                acc[q][2] = __builtin_amdgcn_mfma_f32_16x16x32_f16(A.v, bg[fb + 128], acc[q][2], 0, 0, 0);
                acc[q][3] = __builtin_amdgcn_mfma_f32_16x16x32_f16(A.v, bg[fb + 192], acc[q][3], 0, 0, 0);
            }
        }
    }

    // epilogue: o = qo*16 + lrow plane, pixel = strip_base + lgrp*4 + r (validated r2-r10)
#pragma unroll
    for (int q = 0; q < 2; ++q) {
        float* opb = out + (size_t)n * (O_ * HW) + ((t + (wid << 1) + q) << 7) + tx0 + lgrp * 4;
        *(f32x4*)(opb + (size_t)(0 * 16 + lrow) * HW) = acc[q][0];
        *(f32x4*)(opb + (size_t)(1 * 16 + lrow) * HW) = acc[q][1];
        *(f32x4*)(opb + (size_t)(2 * 16 + lrow) * HW) = acc[q][2];
        *(f32x4*)(opb + (size_t)(3 * 16 + lrow) * HW) = acc[q][3];
    }
}

extern "C" void kernel_launch(void* const* d_in, const int* in_sizes, int n_in,
                              void* d_out, int out_size, void* d_ws, size_t ws_size,
                              hipStream_t stream) {
    const float* x = (const float*)d_in[0];
    const float* off = (const float*)d_in[1];
    const float* w = (const float*)d_in[2];
    float* out = (float*)d_out;

    char* ws = (char*)d_ws;
    unsigned short* bp = (unsigned short*)ws;                       //      73,728 B
    unsigned short* xt = (unsigned short*)(ws + 73728);             //  16,777,216 B
    unsigned* metap = (unsigned*)(ws + 16850944);                   //   4,718,592 B
    unsigned* w01p  = (unsigned*)(ws + 21569536);                   //   4,718,592 B
    unsigned* w23p  = (unsigned*)(ws + 26288128);                   //   4,718,592 B -> 31.0 MB total

    bpack_kernel<<<144, 256, 0, stream>>>(w, bp);
    nchw2nhwc<<<4096, 256, 0, stream>>>(x, xt);
    plan_kernel<<<4608, 256, 0, stream>>>(off, metap, w01p, w23p);

    dcn_mfma<<<1024, 256, 0, stream>>>(xt, metap, w01p, w23p, bp, out);
}

// Round 12
// 61.341 us; speedup vs baseline: 1.0554x; 1.0554x over previous
//
#include <hip/hip_runtime.h>

#define H_ 128
#define W_ 128
#define HW 16384
#define C_ 64
#define O_ 64
#define N_ 8

typedef __attribute__((ext_vector_type(4))) float f32x4;
typedef __attribute__((ext_vector_type(2))) _Float16 f16x2;
typedef __attribute__((ext_vector_type(8))) _Float16 f16x8;

__device__ __forceinline__ unsigned short f2h(float f) {
    union { _Float16 h; unsigned short u; } c;
    c.h = (_Float16)f;
    return c.u;
}

// ---- fused prep: [0,4096) nchw->nhwc f16 ; [4096,8704) tap plan ; [8704,8848) bpack ----
// All section offsets are multiples of 8 so the bid&7 XCD pinning survives.
__global__ __launch_bounds__(256) void prep_all(const float* __restrict__ x,
                                                const float* __restrict__ off,
                                                const float* __restrict__ w,
                                                unsigned short* __restrict__ xt,
                                                unsigned short* __restrict__ bp,
                                                unsigned* __restrict__ metap,
                                                unsigned* __restrict__ w01p,
                                                unsigned* __restrict__ w23p) {
    __shared__ unsigned short tile[32][65];
    const int bid = blockIdx.x;
    const int tid = threadIdx.x;

    if (bid < 4096) {
        // ---- NCHW fp32 -> NHWC f16 (XCD-aligned: n = bid&7) ----
        const int n = bid & 7;
        const int rest = bid >> 3;
        const int wt = rest & 3, h = rest >> 2;
        const int w0 = wt * 32;
        const int wl = tid & 31, cg = tid >> 5;
#pragma unroll
        for (int r = 0; r < 8; ++r) {
            const int c = cg * 8 + r;
            const float v = x[(((size_t)(n * 64 + c) * 128 + h) * 128) + w0 + wl];
            tile[wl][c] = f2h(v);
        }
        __syncthreads();
        const int c2 = tid & 63, wg = tid >> 6;
#pragma unroll
        for (int r = 0; r < 8; ++r) {
            const int ww = wg * 8 + r;
            xt[(((size_t)(n * 128 + h) * 128 + w0 + ww) << 6) + c2] = tile[ww][c2];
        }
    } else if (bid < 8704) {
        // ---- tap plan. Geometry MUST match main: t = ho&~7, tx0 = wo&~7, halo 20x20, margin 6.
        // ok (bit31=1): meta = 0x80000000 | k00(bits0-11) | dx<<12 | dy<<13
        //   k00 = ((sy0*20+sx0)<<2) | (sx0&3) ; consumer idx = k00 ^ lgrp ; dy step +80
        // !ok: meta = gpos<<16 | dx<<1 | dy  (low 12 bits zero -> speculative LDS read in-bounds)
        const int lbid = bid - 4096;       // 4608 = 8n * 9j * 64 pixblocks
        const int n = lbid & 7;
        const int rem = lbid >> 3;
        const int j = rem >> 6;
        const int pix = ((rem & 63) << 8) + tid;
        const int kh = j / 3, kw = j - kh * 3;
        const int ho = pix >> 7, wo = pix & 127;

        const float* ob = off + (size_t)(n * 18 + 2 * j) * HW + pix;
        const float oy = ob[0];
        const float ox = ob[HW];
        const float py = (float)(ho - 1 + kh) + oy;
        const float px = (float)(wo - 1 + kw) + ox;
        const float y0f = floorf(py), x0f = floorf(px);
        const float wy = py - y0f, wx = px - x0f;
        const int y0 = (int)y0f, x0 = (int)x0f;
        const bool vy0 = (unsigned)y0 < 128u;
        const bool vy1 = (unsigned)(y0 + 1) < 128u;
        const bool vx0 = (unsigned)x0 < 128u;
        const bool vx1 = (unsigned)(x0 + 1) < 128u;
        const int y0c = min(max(y0, 0), 127), y1c = min(max(y0 + 1, 0), 127);
        const int x0c = min(max(x0, 0), 127), x1c = min(max(x0 + 1, 0), 127);
        const float s00 = (1.f - wy) * (1.f - wx) * ((vy0 & vx0) ? 1.f : 0.f);
        const float s01 = (1.f - wy) * wx * ((vy0 & vx1) ? 1.f : 0.f);
        const float s10 = wy * (1.f - wx) * ((vy1 & vx0) ? 1.f : 0.f);
        const float s11 = wy * wx * ((vy1 & vx1) ? 1.f : 0.f);

        const int t = ho & ~7, tx0 = wo & ~7;
        const int sy0 = y0c - t + 6, sy1 = y1c - t + 6;
        const int sx0 = x0c - tx0 + 6, sx1 = x1c - tx0 + 6;
        const bool ok = ((unsigned)sy0 <= 19u) & ((unsigned)sy1 <= 19u) &
                        ((unsigned)sx0 <= 19u) & ((unsigned)sx1 <= 19u);
        unsigned meta;
        if (ok) {
            const unsigned k00 = ((unsigned)(sy0 * 20 + sx0) << 2) | (unsigned)(sx0 & 3);
            meta = 0x80000000u | k00 | ((unsigned)(x1c - x0c) << 12) | ((unsigned)(y1c - y0c) << 13);
        } else {
            meta = ((unsigned)(y0c * 128 + x0c) << 16) | ((unsigned)(x1c - x0c) << 1) | (unsigned)(y1c - y0c);
        }
        const size_t e = (size_t)(n * 9 + j) * HW + pix;
        metap[e] = meta;
        w01p[e] = (unsigned)f2h(s00) | ((unsigned)f2h(s01) << 16);
        w23p[e] = (unsigned)f2h(s10) | ((unsigned)f2h(s11) << 16);
    } else {
        // ---- weight -> B-fragment pack ----
        const int idx = (bid - 8704) * 256 + tid;
        if (idx < 36864) {
            const int i = idx & 7;
            const int lane = (idx >> 3) & 63;
            const int ot = (idx >> 9) & 3;
            const int h = (idx >> 11) & 1;
            const int j = idx >> 12;
            const int o = ot * 16 + (lane & 15);
            const int c = h * 32 + (lane >> 4) * 8 + i;
            bp[idx] = f2h(w[(o * 64 + c) * 9 + j]);
        }
    }
}

// ---- main: 8x8 output tile, 2048 blocks -> 6 blocks/CU (LDS 25.6KB, VGPR<=64) ----
// One wave = one 16-pixel strip = 2 rows x 8 cols. pixel idx i -> (row i>>3, col i&7).
__global__ __launch_bounds__(256, 6) void dcn_mfma(const unsigned short* __restrict__ xt,
                                                   const unsigned* __restrict__ metap,
                                                   const unsigned* __restrict__ w01p,
                                                   const unsigned* __restrict__ w23p,
                                                   const unsigned short* __restrict__ bp,
                                                   float* __restrict__ out) {
    __shared__ uint4 lds4[1600];   // 20*20 positions * 4 chunks = 25,600 B

    const int tid = threadIdx.x;
    const int lane = tid & 63;
    const int wid = tid >> 6;
    const int lrow = lane & 15;
    const int lgrp = lane >> 4;

    const int bid = blockIdx.x;
    const int n = bid & 7;
    const int tile = bid >> 3;           // 0..255
    const int t   = (tile >> 4) << 3;    // 16 row-tiles of 8
    const int tx0 = (tile & 15) << 3;    // 16 col-tiles of 8

    const unsigned short* xn = xt + (size_t)n * (HW * 64);
    const unsigned char* xb = (const unsigned char*)xn;
    const f16x8* bg = (const f16x8*)bp;
    const size_t nplane = (size_t)n * 9 * HW;
    const unsigned* mp  = metap + nplane;
    const unsigned* wpa = w01p + nplane;
    const unsigned* wpb = w23p + nplane;

    // lane's pixel: strip = 2 rows x 8 cols
    const int ho = t + (wid << 1) + (lrow >> 3);
    const int pixb = (ho << 7) + tx0 + (lrow & 7);

    f32x4 acc[4];
#pragma unroll
    for (int r = 0; r < 4; ++r) acc[r] = (f32x4){0.f, 0.f, 0.f, 0.f};

#pragma unroll 1
    for (int h = 0; h < 2; ++h) {
        if (h) __syncthreads();
        // stage halo half (32 ch): 400 positions, coalesced, x-swizzled
        for (int c = tid; c < 400; c += 256) {
            const int ry = c / 20, rx = c - ry * 20;
            const int gy = min(max(t - 6 + ry, 0), 127);
            const int gx = min(max(tx0 - 6 + rx, 0), 127);
            const uint4* src = (const uint4*)(xn + ((((gy << 7) + gx) << 6) | (h << 5)));
            const int d = c << 2, sw = rx & 3;
#pragma unroll
            for (int sub = 0; sub < 4; ++sub) lds4[d + (sub ^ sw)] = src[sub];
        }
        __syncthreads();

#pragma unroll 3
        for (int j = 0; j < 9; ++j) {
            const int e = j * HW + pixb;
            const unsigned meta = mp[e];
            const unsigned wab = wpa[e];
            const unsigned wcd = wpb[e];
            union { unsigned u; f16x2 h2; } W00, W01, W10, W11;
            W00.u = __builtin_amdgcn_perm(wab, wab, 0x01000100u);
            W01.u = __builtin_amdgcn_perm(wab, wab, 0x03020302u);
            W10.u = __builtin_amdgcn_perm(wcd, wcd, 0x01000100u);
            W11.u = __builtin_amdgcn_perm(wcd, wcd, 0x03020302u);

            const bool ok = (int)meta < 0;
            const unsigned k00 = meta & 0xfffu;
            const unsigned dx = (meta >> 12) & 1u;
            const unsigned k01 = ((k00 & ~3u) + (dx << 2)) | (((k00 & 3u) + dx) & 3u);
            const unsigned dyi = (meta & 0x2000u) ? 80u : 0u;
            const unsigned k10 = k00 + dyi, k11 = k01 + dyi;

            uint4 T00 = lds4[k00 ^ (unsigned)lgrp];
            uint4 T01 = lds4[k01 ^ (unsigned)lgrp];
            uint4 T10 = lds4[k10 ^ (unsigned)lgrp];
            uint4 T11 = lds4[k11 ^ (unsigned)lgrp];
            if (!__all(ok)) {   // rare: tap beyond halo -> exact global path
                if (!ok) {
                    const unsigned gpos = (meta >> 16) & 0x3fffu;
                    const int dxo = (int)((meta >> 1) & 1u) << 7;
                    const int dyo = (int)(meta & 1u) << 14;
                    const unsigned char* p = xb + ((gpos << 7) | (h << 6)) + (lgrp << 4);
                    T00 = *(const uint4*)p;
                    T01 = *(const uint4*)(p + dxo);
                    T10 = *(const uint4*)(p + dyo);
                    T11 = *(const uint4*)(p + dyo + dxo);
                }
            }
            union { uint4 u; f16x2 h2[4]; f16x8 v; } A, U00, U01, U10, U11;
            U00.u = T00; U01.u = T01; U10.u = T10; U11.u = T11;
#pragma unroll
            for (int k = 0; k < 4; ++k)
                A.h2[k] = U00.h2[k] * W00.h2 + U01.h2[k] * W01.h2
                        + U10.h2[k] * W10.h2 + U11.h2[k] * W11.h2;
            const int fb = ((j * 2 + h) << 8) + lane;
            acc[0] = __builtin_amdgcn_mfma_f32_16x16x32_f16(A.v, bg[fb],       acc[0], 0, 0, 0);
            acc[1] = __builtin_amdgcn_mfma_f32_16x16x32_f16(A.v, bg[fb + 64],  acc[1], 0, 0, 0);
            acc[2] = __builtin_amdgcn_mfma_f32_16x16x32_f16(A.v, bg[fb + 128], acc[2], 0, 0, 0);
            acc[3] = __builtin_amdgcn_mfma_f32_16x16x32_f16(A.v, bg[fb + 192], acc[3], 0, 0, 0);
        }
    }

    // epilogue: D row = pixel-in-strip = lgrp*4 + r -> (row lgrp>>1, col (lgrp&1)*4 + r);
    // D col = o = qq*16 + lrow. (layout validated r2-r11)
    const int orow = t + (wid << 1) + (lgrp >> 1);
    float* opb = out + (size_t)n * (O_ * HW) + ((size_t)orow << 7) + tx0 + ((lgrp & 1) << 2);
#pragma unroll
    for (int qq = 0; qq < 4; ++qq)
        *(f32x4*)(opb + (size_t)(qq * 16 + lrow) * HW) = acc[qq];
}

extern "C" void kernel_launch(void* const* d_in, const int* in_sizes, int n_in,
                              void* d_out, int out_size, void* d_ws, size_t ws_size,
                              hipStream_t stream) {
    const float* x = (const float*)d_in[0];
    const float* off = (const float*)d_in[1];
    const float* w = (const float*)d_in[2];
    float* out = (float*)d_out;

    char* ws = (char*)d_ws;
    unsigned short* bp = (unsigned short*)ws;                       //      73,728 B
    unsigned short* xt = (unsigned short*)(ws + 73728);             //  16,777,216 B
    unsigned* metap = (unsigned*)(ws + 16850944);                   //   4,718,592 B
    unsigned* w01p  = (unsigned*)(ws + 21569536);                   //   4,718,592 B
    unsigned* w23p  = (unsigned*)(ws + 26288128);                   //   4,718,592 B -> 31.0 MB

    prep_all<<<8848, 256, 0, stream>>>(x, off, w, xt, bp, metap, w01p, w23p);
    dcn_mfma<<<2048, 256, 0, stream>>>(xt, metap, w01p, w23p, bp, out);
}

// Round 13
// 57.505 us; speedup vs baseline: 1.1258x; 1.0667x over previous
//
#include <hip/hip_runtime.h>

#define H_ 128
#define W_ 128
#define HW 16384
#define C_ 64
#define O_ 64
#define N_ 8

typedef __attribute__((ext_vector_type(4))) float f32x4;
typedef __attribute__((ext_vector_type(2))) _Float16 f16x2;
typedef __attribute__((ext_vector_type(8))) _Float16 f16x8;

__device__ __forceinline__ unsigned short f2h(float f) {
    union { _Float16 h; unsigned short u; } c;
    c.h = (_Float16)f;
    return c.u;
}

// ---- fused prep: [0,4096) nchw->nhwc f16 ; [4096,8704) tap plan ; [8704,8848) bpack ----
// Section offsets are multiples of 8 so the bid&7 XCD pinning survives.
// Plan geometry matches the 16(w)x8(h) main tile: t = ho&~7, tx0 = wo&~15,
// halo 20(y)x28(x), margin 6, k00 row stride 28 positions (dy step 112 chunks).
__global__ __launch_bounds__(256) void prep_all(const float* __restrict__ x,
                                                const float* __restrict__ off,
                                                const float* __restrict__ w,
                                                unsigned short* __restrict__ xt,
                                                unsigned short* __restrict__ bp,
                                                unsigned* __restrict__ metap,
                                                unsigned* __restrict__ w01p,
                                                unsigned* __restrict__ w23p) {
    __shared__ unsigned short tile[32][65];
    const int bid = blockIdx.x;
    const int tid = threadIdx.x;

    if (bid < 4096) {
        // ---- NCHW fp32 -> NHWC f16 (XCD-aligned: n = bid&7) ----
        const int n = bid & 7;
        const int rest = bid >> 3;
        const int wt = rest & 3, h = rest >> 2;
        const int w0 = wt * 32;
        const int wl = tid & 31, cg = tid >> 5;
#pragma unroll
        for (int r = 0; r < 8; ++r) {
            const int c = cg * 8 + r;
            const float v = x[(((size_t)(n * 64 + c) * 128 + h) * 128) + w0 + wl];
            tile[wl][c] = f2h(v);
        }
        __syncthreads();
        const int c2 = tid & 63, wg = tid >> 6;
#pragma unroll
        for (int r = 0; r < 8; ++r) {
            const int ww = wg * 8 + r;
            xt[(((size_t)(n * 128 + h) * 128 + w0 + ww) << 6) + c2] = tile[ww][c2];
        }
    } else if (bid < 8704) {
        // ---- tap plan (16x8 tile geometry) ----
        // ok (bit31=1): meta = 0x80000000 | k00(bits0-11) | dx<<12 | dy<<13
        //   k00 = ((sy0*28+sx0)<<2) | (sx0&3) ; consumer idx = k00 ^ lgrp ; dy step +112
        // !ok: meta = gpos<<16 | dx<<1 | dy  (low 12 bits zero -> speculative LDS read in-bounds)
        const int lbid = bid - 4096;       // 4608 = 8n * 9j * 64 pixblocks
        const int n = lbid & 7;
        const int rem = lbid >> 3;
        const int j = rem >> 6;
        const int pix = ((rem & 63) << 8) + tid;
        const int kh = j / 3, kw = j - kh * 3;
        const int ho = pix >> 7, wo = pix & 127;

        const float* ob = off + (size_t)(n * 18 + 2 * j) * HW + pix;
        const float oy = ob[0];
        const float ox = ob[HW];
        const float py = (float)(ho - 1 + kh) + oy;
        const float px = (float)(wo - 1 + kw) + ox;
        const float y0f = floorf(py), x0f = floorf(px);
        const float wy = py - y0f, wx = px - x0f;
        const int y0 = (int)y0f, x0 = (int)x0f;
        const bool vy0 = (unsigned)y0 < 128u;
        const bool vy1 = (unsigned)(y0 + 1) < 128u;
        const bool vx0 = (unsigned)x0 < 128u;
        const bool vx1 = (unsigned)(x0 + 1) < 128u;
        const int y0c = min(max(y0, 0), 127), y1c = min(max(y0 + 1, 0), 127);
        const int x0c = min(max(x0, 0), 127), x1c = min(max(x0 + 1, 0), 127);
        const float s00 = (1.f - wy) * (1.f - wx) * ((vy0 & vx0) ? 1.f : 0.f);
        const float s01 = (1.f - wy) * wx * ((vy0 & vx1) ? 1.f : 0.f);
        const float s10 = wy * (1.f - wx) * ((vy1 & vx0) ? 1.f : 0.f);
        const float s11 = wy * wx * ((vy1 & vx1) ? 1.f : 0.f);

        const int t = ho & ~7, tx0 = wo & ~15;
        const int sy0 = y0c - t + 6, sy1 = y1c - t + 6;
        const int sx0 = x0c - tx0 + 6, sx1 = x1c - tx0 + 6;
        const bool ok = ((unsigned)sy0 <= 19u) & ((unsigned)sy1 <= 19u) &
                        ((unsigned)sx0 <= 27u) & ((unsigned)sx1 <= 27u);
        unsigned meta;
        if (ok) {
            const unsigned k00 = ((unsigned)(sy0 * 28 + sx0) << 2) | (unsigned)(sx0 & 3);
            meta = 0x80000000u | k00 | ((unsigned)(x1c - x0c) << 12) | ((unsigned)(y1c - y0c) << 13);
        } else {
            meta = ((unsigned)(y0c * 128 + x0c) << 16) | ((unsigned)(x1c - x0c) << 1) | (unsigned)(y1c - y0c);
        }
        const size_t e = (size_t)(n * 9 + j) * HW + pix;
        metap[e] = meta;
        w01p[e] = (unsigned)f2h(s00) | ((unsigned)f2h(s01) << 16);
        w23p[e] = (unsigned)f2h(s10) | ((unsigned)f2h(s11) << 16);
    } else {
        // ---- weight -> B-fragment pack ----
        const int idx = (bid - 8704) * 256 + tid;
        if (idx < 36864) {
            const int i = idx & 7;
            const int lane = (idx >> 3) & 63;
            const int ot = (idx >> 9) & 3;
            const int h = (idx >> 11) & 1;
            const int j = idx >> 12;
            const int o = ot * 16 + (lane & 15);
            const int c = h * 32 + (lane >> 4) * 8 + i;
            bp[idx] = f2h(w[(o * 64 + c) * 9 + j]);
        }
    }
}

// ---- main: 16(w)x8(h) tile, 1024 blocks = 4/CU; coords from precomputed plan ----
// (tile-size scan: 16x16 -> 61us, 16x8 -> 45us, 8x8 -> 50us; 16x8 is the
//  optimum of staging-redundancy vs occupancy.)
__global__ __launch_bounds__(256, 4) void dcn_mfma(const unsigned short* __restrict__ xt,
                                                   const unsigned* __restrict__ metap,
                                                   const unsigned* __restrict__ w01p,
                                                   const unsigned* __restrict__ w23p,
                                                   const unsigned short* __restrict__ bp,
                                                   float* __restrict__ out) {
    __shared__ uint4 lds4[2240];   // 20*28 positions * 4 chunks (one 32-ch half)

    const int tid = threadIdx.x;
    const int lane = tid & 63;
    const int wid = tid >> 6;
    const int lrow = lane & 15;
    const int lgrp = lane >> 4;

    const int bid = blockIdx.x;
    const int n = bid & 7;
    const int tile = bid >> 3;
    const int t   = (tile >> 3) << 3;
    const int tx0 = (tile & 7) << 4;

    const unsigned short* xn = xt + (size_t)n * (HW * 64);
    const unsigned char* xb = (const unsigned char*)xn;
    const f16x8* bg = (const f16x8*)bp;
    const size_t nplane = (size_t)n * 9 * HW;
    const unsigned* mp  = metap + nplane;
    const unsigned* wpa = w01p + nplane;
    const unsigned* wpb = w23p + nplane;

    f32x4 acc[2][4];
#pragma unroll
    for (int q = 0; q < 2; ++q)
#pragma unroll
        for (int r = 0; r < 4; ++r) acc[q][r] = (f32x4){0.f, 0.f, 0.f, 0.f};

#pragma unroll 1
    for (int h = 0; h < 2; ++h) {
        if (h) __syncthreads();
        for (int c = tid; c < 560; c += 256) {
            const int ry = c / 28, rx = c - ry * 28;
            const int gy = min(max(t - 6 + ry, 0), 127);
            const int gx = min(max(tx0 - 6 + rx, 0), 127);
            const uint4* src = (const uint4*)(xn + ((((gy << 7) + gx) << 6) | (h << 5)));
            const int d = c << 2, sw = rx & 3;
#pragma unroll
            for (int sub = 0; sub < 4; ++sub) lds4[d + (sub ^ sw)] = src[sub];
        }
        __syncthreads();

#pragma unroll
        for (int q = 0; q < 2; ++q) {
            const int ho = t + (wid << 1) + q;
            const int pixb = (ho << 7) + tx0 + lrow;

#pragma unroll 3
            for (int j = 0; j < 9; ++j) {
                const int e = j * HW + pixb;
                const unsigned meta = mp[e];
                const unsigned wab = wpa[e];
                const unsigned wcd = wpb[e];
                union { unsigned u; f16x2 h2; } W00, W01, W10, W11;
                W00.u = __builtin_amdgcn_perm(wab, wab, 0x01000100u);
                W01.u = __builtin_amdgcn_perm(wab, wab, 0x03020302u);
                W10.u = __builtin_amdgcn_perm(wcd, wcd, 0x01000100u);
                W11.u = __builtin_amdgcn_perm(wcd, wcd, 0x03020302u);

                const bool ok = (int)meta < 0;
                const unsigned k00 = meta & 0xfffu;
                const unsigned dx = (meta >> 12) & 1u;
                const unsigned k01 = ((k00 & ~3u) + (dx << 2)) | (((k00 & 3u) + dx) & 3u);
                const unsigned dyi = (meta & 0x2000u) ? 112u : 0u;
                const unsigned k10 = k00 + dyi, k11 = k01 + dyi;

                uint4 T00 = lds4[k00 ^ (unsigned)lgrp];
                uint4 T01 = lds4[k01 ^ (unsigned)lgrp];
                uint4 T10 = lds4[k10 ^ (unsigned)lgrp];
                uint4 T11 = lds4[k11 ^ (unsigned)lgrp];
                if (!__all(ok)) {   // rare: tap beyond halo -> exact global path
                    if (!ok) {
                        const unsigned gpos = (meta >> 16) & 0x3fffu;
                        const int dxo = (int)((meta >> 1) & 1u) << 7;
                        const int dyo = (int)(meta & 1u) << 14;
                        const unsigned char* p = xb + ((gpos << 7) | (h << 6)) + (lgrp << 4);
                        T00 = *(const uint4*)p;
                        T01 = *(const uint4*)(p + dxo);
                        T10 = *(const uint4*)(p + dyo);
                        T11 = *(const uint4*)(p + dyo + dxo);
                    }
                }
                union { uint4 u; f16x2 h2[4]; f16x8 v; } A, U00, U01, U10, U11;
                U00.u = T00; U01.u = T01; U10.u = T10; U11.u = T11;
#pragma unroll
                for (int k = 0; k < 4; ++k)
                    A.h2[k] = U00.h2[k] * W00.h2 + U01.h2[k] * W01.h2
                            + U10.h2[k] * W10.h2 + U11.h2[k] * W11.h2;
                const int fb = ((j * 2 + h) << 8) + lane;
                acc[q][0] = __builtin_amdgcn_mfma_f32_16x16x32_f16(A.v, bg[fb],       acc[q][0], 0, 0, 0);
                acc[q][1] = __builtin_amdgcn_mfma_f32_16x16x32_f16(A.v, bg[fb + 64],  acc[q][1], 0, 0, 0);
                acc[q][2] = __builtin_amdgcn_mfma_f32_16x16x32_f16(A.v, bg[fb + 128], acc[q][2], 0, 0, 0);
                acc[q][3] = __builtin_amdgcn_mfma_f32_16x16x32_f16(A.v, bg[fb + 192], acc[q][3], 0, 0, 0);
            }
        }
    }

    // epilogue: o = qq*16 + lrow plane, pixel = strip_base + lgrp*4 + r (validated r2-r12)
#pragma unroll
    for (int q = 0; q < 2; ++q) {
        float* opb = out + (size_t)n * (O_ * HW) + ((t + (wid << 1) + q) << 7) + tx0 + lgrp * 4;
        *(f32x4*)(opb + (size_t)(0 * 16 + lrow) * HW) = acc[q][0];
        *(f32x4*)(opb + (size_t)(1 * 16 + lrow) * HW) = acc[q][1];
        *(f32x4*)(opb + (size_t)(2 * 16 + lrow) * HW) = acc[q][2];
        *(f32x4*)(opb + (size_t)(3 * 16 + lrow) * HW) = acc[q][3];
    }
}

extern "C" void kernel_launch(void* const* d_in, const int* in_sizes, int n_in,
                              void* d_out, int out_size, void* d_ws, size_t ws_size,
                              hipStream_t stream) {
    const float* x = (const float*)d_in[0];
    const float* off = (const float*)d_in[1];
    const float* w = (const float*)d_in[2];
    float* out = (float*)d_out;

    char* ws = (char*)d_ws;
    unsigned short* bp = (unsigned short*)ws;                       //      73,728 B
    unsigned short* xt = (unsigned short*)(ws + 73728);             //  16,777,216 B
    unsigned* metap = (unsigned*)(ws + 16850944);                   //   4,718,592 B
    unsigned* w01p  = (unsigned*)(ws + 21569536);                   //   4,718,592 B
    unsigned* w23p  = (unsigned*)(ws + 26288128);                   //   4,718,592 B -> 31.0 MB

    prep_all<<<8848, 256, 0, stream>>>(x, off, w, xt, bp, metap, w01p, w23p);
    dcn_mfma<<<1024, 256, 0, stream>>>(xt, metap, w01p, w23p, bp, out);
}